// Round 1
// baseline (410.358 us; speedup 1.0000x reference)
//
#include <hip/hip_runtime.h>

// FBPinn 1D, NW=16 windows, MLP 1->64->64->64->1 (tanh), sigmoid windows.
// Strategy:
//   pass1: bucket point indices per window (each point is in 1-2 windows).
//   pass2: one window per block-column -> weight addresses are wave-uniform
//          (scalar loads), full fp32 MLP per point in registers.
// Workspace layout: int cnt[16] @0, int list[16*CAP] @64.  ~656 KB needed.

#define NW   16
#define NEUR 64
#define CAP  10240   // expected max per-window count ~7.9k; 10240 is >20 sigma

__device__ __forceinline__ float fast_tanh(float x) {
    // tanh(x) = 1 - 2/(exp(2x)+1); exact limits at +-inf
    float e = __expf(x + x);
    return 1.0f - 2.0f * __builtin_amdgcn_rcpf(e + 1.0f);
}
__device__ __forceinline__ float fast_sigmoid(float z) {
    return __builtin_amdgcn_rcpf(1.0f + __expf(-z));
}

__global__ __launch_bounds__(256) void pass1_bucket(
    const float* __restrict__ x, int n,
    int* __restrict__ cnt, int* __restrict__ list) {
    int i = blockIdx.x * blockDim.x + threadIdx.x;
    if (i >= n) return;
    float xv = x[i];
    #pragma unroll
    for (int w = 0; w < NW; ++w) {
        float lo = (w == 0)      ? 0.0f   : ((float)w - 0.125f) * 6.25f;
        float hi = (w == NW - 1) ? 100.0f : ((float)w + 1.125f) * 6.25f;
        if (lo < xv && xv < hi) {
            int pos = atomicAdd(&cnt[w], 1);
            if (pos < CAP) list[w * CAP + pos] = i;
        }
    }
}

__global__ __launch_bounds__(256) void pass2_mlp(
    const float* __restrict__ x,
    const float* __restrict__ W_in, const float* __restrict__ b_in,
    const float* __restrict__ W_h,  const float* __restrict__ b_h,
    const float* __restrict__ W_out, const float* __restrict__ b_out,
    const int* __restrict__ cnt, const int* __restrict__ list,
    float* __restrict__ out) {
    const int w = blockIdx.y;                     // window id: wave-uniform
    const int count = min(cnt[w], CAP);

    float lo = (w == 0)      ? 0.0f   : ((float)w - 0.125f) * 6.25f;
    float hi = (w == NW - 1) ? 100.0f : ((float)w + 1.125f) * 6.25f;
    float mean    = 0.5f * (lo + hi);
    float stdv    = 0.5f * (hi - lo);
    float inv_std = 1.0f / stdv;                  // full-precision div, once
    float ow0 = (float)w * 6.25f;                 // ovm[w]   = w*width exactly
    float ow1 = (float)(w + 1) * 6.25f;           // ovm[w+1]

    const float* Wi = W_in  + w * NEUR;
    const float* bi = b_in  + w * NEUR;
    const float* W0 = W_h   + (0 * NW + w) * NEUR * NEUR;
    const float* b0 = b_h   + (0 * NW + w) * NEUR;
    const float* W1 = W_h   + (1 * NW + w) * NEUR * NEUR;
    const float* b1 = b_h   + (1 * NW + w) * NEUR;
    const float* Wo = W_out + w * NEUR;
    const float bo  = b_out[w];

    for (int base = blockIdx.x * blockDim.x; base < count;
         base += blockDim.x * gridDim.x) {
        int k = base + threadIdx.x;
        if (k < count) {
            int   i  = list[w * CAP + k];
            float xv = x[i];
            float xn = (xv - mean) * inv_std;

            float h[NEUR];
            #pragma unroll
            for (int o = 0; o < NEUR; ++o)
                h[o] = fast_tanh(fmaf(xn, Wi[o], bi[o]));

            // hidden layer 1
            float a[NEUR];
            #pragma unroll
            for (int o = 0; o < NEUR; ++o) a[o] = b0[o];
            #pragma unroll 8
            for (int ii = 0; ii < NEUR; ++ii) {
                float hv = h[ii];
                #pragma unroll
                for (int o = 0; o < NEUR; ++o)
                    a[o] = fmaf(hv, W0[ii * NEUR + o], a[o]);
            }
            #pragma unroll
            for (int o = 0; o < NEUR; ++o) h[o] = fast_tanh(a[o]);

            // hidden layer 2
            #pragma unroll
            for (int o = 0; o < NEUR; ++o) a[o] = b1[o];
            #pragma unroll 8
            for (int ii = 0; ii < NEUR; ++ii) {
                float hv = h[ii];
                #pragma unroll
                for (int o = 0; o < NEUR; ++o)
                    a[o] = fmaf(hv, W1[ii * NEUR + o], a[o]);
            }
            #pragma unroll
            for (int o = 0; o < NEUR; ++o) h[o] = fast_tanh(a[o]);

            // output layer
            float outv = bo;
            #pragma unroll
            for (int o = 0; o < NEUR; ++o)
                outv = fmaf(h[o], Wo[o], outv);

            // sigmoid window (SIGMA = 0.5 -> multiply by 2)
            float win = fast_sigmoid((xv - ow0) * 2.0f) *
                        fast_sigmoid((ow1 - xv) * 2.0f);

            atomicAdd(&out[i], win * outv);
        }
    }
}

extern "C" void kernel_launch(void* const* d_in, const int* in_sizes, int n_in,
                              void* d_out, int out_size, void* d_ws, size_t ws_size,
                              hipStream_t stream) {
    const float* x     = (const float*)d_in[0];
    const float* W_in  = (const float*)d_in[1];
    const float* b_in  = (const float*)d_in[2];
    const float* W_h   = (const float*)d_in[3];
    const float* b_h   = (const float*)d_in[4];
    const float* W_out = (const float*)d_in[5];
    const float* b_out = (const float*)d_in[6];
    float* out = (float*)d_out;
    const int n = in_sizes[0];

    int* cnt  = (int*)d_ws;                 // 16 ints
    int* list = (int*)((char*)d_ws + 64);   // 16*CAP ints

    hipMemsetAsync(cnt, 0, NW * sizeof(int), stream);
    hipMemsetAsync(out, 0, (size_t)n * sizeof(float), stream);

    pass1_bucket<<<(n + 255) / 256, 256, 0, stream>>>(x, n, cnt, list);

    dim3 grid(32, NW);   // 512 blocks, 2 blocks/CU
    pass2_mlp<<<grid, 256, 0, stream>>>(x, W_in, b_in, W_h, b_h, W_out, b_out,
                                        cnt, list, out);
}

// Round 2
// 139.712 us; speedup vs baseline: 2.9372x; 2.9372x over previous
//
#include <hip/hip_runtime.h>

// FBPinn 1D, NW=16 windows, MLP 1->64->64->64->1 (tanh), sigmoid windows.
//   pass1: bucket point indices per window via LDS histogram + one global
//          atomic per (window, block)  [R1: flat global atomics to one
//          cacheline cost 283 us at VALUBusy=0.2% -- pure L2 atomic serialize]
//   pass2: one window per block-column -> weight addresses wave-uniform,
//          full fp32 MLP per point in registers.
// Workspace: int cnt[16*16] (64B stride/window) @0, int list[16*CAP] @1024.

#define NW    16
#define NEUR  64
#define CAP   10240       // max per-window count ~7.9k; generous headroom
#define CSTR  16          // cnt stride in ints -> 64B, one cacheline/window

__device__ __forceinline__ float fast_tanh(float x) {
    float e = __expf(x + x);
    return 1.0f - 2.0f * __builtin_amdgcn_rcpf(e + 1.0f);
}
__device__ __forceinline__ float fast_sigmoid(float z) {
    return __builtin_amdgcn_rcpf(1.0f + __expf(-z));
}

__global__ __launch_bounds__(256) void pass1_bucket(
    const float* __restrict__ x, int n,
    int* __restrict__ cnt, int* __restrict__ list) {
    __shared__ int lcnt[NW];
    __shared__ int lbase[NW];
    const int tid = threadIdx.x;
    if (tid < NW) lcnt[tid] = 0;
    __syncthreads();

    const int i = blockIdx.x * 256 + tid;
    int myw[2] = {-1, -1};
    int mypos[2] = {0, 0};
    if (i < n) {
        float xv = x[i];
        int nf = 0;
        #pragma unroll
        for (int w = 0; w < NW; ++w) {
            float lo = (w == 0)      ? 0.0f   : ((float)w - 0.125f) * 6.25f;
            float hi = (w == NW - 1) ? 100.0f : ((float)w + 1.125f) * 6.25f;
            if (lo < xv && xv < hi && nf < 2) {
                myw[nf]   = w;
                mypos[nf] = atomicAdd(&lcnt[w], 1);   // LDS atomic: cheap
                ++nf;
            }
        }
    }
    __syncthreads();
    if (tid < NW)
        lbase[tid] = atomicAdd(&cnt[tid * CSTR], lcnt[tid]);  // 16/block
    __syncthreads();

    #pragma unroll
    for (int f = 0; f < 2; ++f) {
        int w = myw[f];
        if (w >= 0) {
            int p = lbase[w] + mypos[f];
            if (p < CAP) list[w * CAP + p] = i;
        }
    }
}

__global__ __launch_bounds__(256) void pass2_mlp(
    const float* __restrict__ x,
    const float* __restrict__ W_in, const float* __restrict__ b_in,
    const float* __restrict__ W_h,  const float* __restrict__ b_h,
    const float* __restrict__ W_out, const float* __restrict__ b_out,
    const int* __restrict__ cnt, const int* __restrict__ list,
    float* __restrict__ out) {
    const int w = blockIdx.y;                     // window id: wave-uniform
    const int count = min(cnt[w * CSTR], CAP);

    float lo = (w == 0)      ? 0.0f   : ((float)w - 0.125f) * 6.25f;
    float hi = (w == NW - 1) ? 100.0f : ((float)w + 1.125f) * 6.25f;
    float mean    = 0.5f * (lo + hi);
    float stdv    = 0.5f * (hi - lo);
    float inv_std = 1.0f / stdv;
    float ow0 = (float)w * 6.25f;                 // ovm[w] exactly
    float ow1 = (float)(w + 1) * 6.25f;

    const float* Wi = W_in  + w * NEUR;
    const float* bi = b_in  + w * NEUR;
    const float* W0 = W_h   + (0 * NW + w) * NEUR * NEUR;
    const float* b0 = b_h   + (0 * NW + w) * NEUR;
    const float* W1 = W_h   + (1 * NW + w) * NEUR * NEUR;
    const float* b1 = b_h   + (1 * NW + w) * NEUR;
    const float* Wo = W_out + w * NEUR;
    const float bo  = b_out[w];

    for (int base = blockIdx.x * blockDim.x; base < count;
         base += blockDim.x * gridDim.x) {
        int k = base + threadIdx.x;
        if (k < count) {
            int   i  = list[w * CAP + k];
            float xv = x[i];
            float xn = (xv - mean) * inv_std;

            float h[NEUR];
            #pragma unroll
            for (int o = 0; o < NEUR; ++o)
                h[o] = fast_tanh(fmaf(xn, Wi[o], bi[o]));

            float a[NEUR];
            #pragma unroll
            for (int o = 0; o < NEUR; ++o) a[o] = b0[o];
            #pragma unroll 8
            for (int ii = 0; ii < NEUR; ++ii) {
                float hv = h[ii];
                #pragma unroll
                for (int o = 0; o < NEUR; ++o)
                    a[o] = fmaf(hv, W0[ii * NEUR + o], a[o]);
            }
            #pragma unroll
            for (int o = 0; o < NEUR; ++o) h[o] = fast_tanh(a[o]);

            #pragma unroll
            for (int o = 0; o < NEUR; ++o) a[o] = b1[o];
            #pragma unroll 8
            for (int ii = 0; ii < NEUR; ++ii) {
                float hv = h[ii];
                #pragma unroll
                for (int o = 0; o < NEUR; ++o)
                    a[o] = fmaf(hv, W1[ii * NEUR + o], a[o]);
            }
            #pragma unroll
            for (int o = 0; o < NEUR; ++o) h[o] = fast_tanh(a[o]);

            float outv = bo;
            #pragma unroll
            for (int o = 0; o < NEUR; ++o)
                outv = fmaf(h[o], Wo[o], outv);

            float win = fast_sigmoid((xv - ow0) * 2.0f) *
                        fast_sigmoid((ow1 - xv) * 2.0f);

            atomicAdd(&out[i], win * outv);
        }
    }
}

extern "C" void kernel_launch(void* const* d_in, const int* in_sizes, int n_in,
                              void* d_out, int out_size, void* d_ws, size_t ws_size,
                              hipStream_t stream) {
    const float* x     = (const float*)d_in[0];
    const float* W_in  = (const float*)d_in[1];
    const float* b_in  = (const float*)d_in[2];
    const float* W_h   = (const float*)d_in[3];
    const float* b_h   = (const float*)d_in[4];
    const float* W_out = (const float*)d_in[5];
    const float* b_out = (const float*)d_in[6];
    float* out = (float*)d_out;
    const int n = in_sizes[0];

    int* cnt  = (int*)d_ws;                     // 16*16 ints (64B/window)
    int* list = (int*)((char*)d_ws + 1024);     // 16*CAP ints

    hipMemsetAsync(cnt, 0, NW * CSTR * sizeof(int), stream);
    hipMemsetAsync(out, 0, (size_t)n * sizeof(float), stream);

    pass1_bucket<<<(n + 255) / 256, 256, 0, stream>>>(x, n, cnt, list);

    dim3 grid(32, NW);   // 8192 slots/window >= max count ~7.9k
    pass2_mlp<<<grid, 256, 0, stream>>>(x, W_in, b_in, W_h, b_h, W_out, b_out,
                                        cnt, list, out);
}